// Round 4
// baseline (250.667 us; speedup 1.0000x reference)
//
#include <hip/hip_runtime.h>
#include <math.h>

// Problem constants (match reference file)
#define NB 16
#define NPIX 1048576                       // 1024*1024
#define BINS 2048
#define CHUNKS 64                          // blocks per sample in pass A
#define TPB_A 1024
#define PIX_PER_BLOCK (NPIX / CHUNKS)      // 16384 = 1024 thr * 16 px
#define QUADS 4                            // 4 float4-quads per thread = 16 px
#define REPL 8                             // histogram replicas per sample
#define TPB_B 256
#define BINS_PER_CHUNK (BINS / TPB_B)      // 8
#define BLOSS_MAX 16.7f                    // > B_CAP
#define BINW (BLOSS_MAX / (float)BINS)
#define B_CAP 16.636f                      // -log(2^-24): max -log(1-pc) after clip
#define F_CAP 16.1181f                     // -log(1e-7f)

__device__ __forceinline__ void fadd_glb(float* p, float v) {
    __hip_atomic_fetch_add(p, v, __ATOMIC_RELAXED, __HIP_MEMORY_SCOPE_AGENT);
}

__global__ __launch_bounds__(TPB_A, 8) void pass_a(
    const float* __restrict__ probs, const float* __restrict__ gt,
    unsigned* __restrict__ g_cnt, float* __restrict__ f_sum,
    float* __restrict__ b_sum)
{
    __shared__ unsigned s_cnt[BINS];              // 8 KB count histogram
    __shared__ float s_redf[TPB_A / 64];
    __shared__ float s_redb[TPB_A / 64];

    const int tid = threadIdx.x;
    #pragma unroll
    for (int j = 0; j < BINS / TPB_A; ++j) s_cnt[j * TPB_A + tid] = 0u;
    __syncthreads();

    const int blk = blockIdx.x;
    const int b = blk / CHUNKS;
    const int chunk = blk % CHUNKS;
    const float* p0 = probs + (size_t)b * 2 * NPIX;
    const float* p1 = p0 + NPIX;
    const float* gp = gt + (size_t)b * NPIX;
    const int base = chunk * PIX_PER_BLOCK;
    const float scale = (float)BINS / BLOSS_MAX;

    // ---- issue ALL 12 loads as one burst (whole per-thread workload) ----
    float4 A0[QUADS], A1[QUADS], G[QUADS];
    #pragma unroll
    for (int q = 0; q < QUADS; ++q) {
        const int i = base + ((q * TPB_A + tid) << 2);
        A0[q] = *(const float4*)(p0 + i);
        A1[q] = *(const float4*)(p1 + i);
        G[q]  = *(const float4*)(gp + i);
    }

    float f_acc = 0.f, b_acc = 0.f;
    #pragma unroll
    for (int q = 0; q < QUADS; ++q) {
        const float dv[4] = {A1[q].x - A0[q].x, A1[q].y - A0[q].y,
                             A1[q].z - A0[q].z, A1[q].w - A0[q].w};
        const float gv[4] = {G[q].x, G[q].y, G[q].z, G[q].w};
        #pragma unroll
        for (int c = 0; c < 4; ++c) {
            // -log(1-sigmoid(d)) = softplus(d); -log(sigmoid(d)) = softplus(d)-d
            const float d = dv[c];
            const float g = gv[c];                 // exactly 0.0 or 1.0
            const float sp = fmaxf(d, 0.f) + __logf(1.f + __expf(-fabsf(d)));
            f_acc += g * fminf(sp - d, F_CAP);     // branchless fg loss
            const float bl = fminf(sp, B_CAP);
            b_acc += (1.f - g) * bl;               // branchless bg total
            if (g < 0.5f) {                        // only the atomic is predicated
                int bin = (int)(bl * scale);
                bin = bin < (BINS - 1) ? bin : (BINS - 1);
                atomicAdd(&s_cnt[bin], 1u);
            }
        }
    }
    __syncthreads();

    // flush count histogram into one of 8 replicated per-sample histograms
    {
        unsigned* dst = g_cnt + ((size_t)b * REPL + (chunk & (REPL - 1))) * BINS;
        #pragma unroll
        for (int j = 0; j < BINS / TPB_A; ++j) {
            const int bin = j * TPB_A + tid;
            const unsigned c = s_cnt[bin];
            if (c) atomicAdd(&dst[bin], c);
        }
    }

    // block-reduce f_acc / b_acc
    #pragma unroll
    for (int o = 32; o > 0; o >>= 1) {
        f_acc += __shfl_down(f_acc, o, 64);
        b_acc += __shfl_down(b_acc, o, 64);
    }
    if ((tid & 63) == 0) { s_redf[tid >> 6] = f_acc; s_redb[tid >> 6] = b_acc; }
    __syncthreads();
    if (tid == 0) {
        float f = 0.f, bs = 0.f;
        #pragma unroll
        for (int w = 0; w < TPB_A / 64; ++w) { f += s_redf[w]; bs += s_redb[w]; }
        fadd_glb(&f_sum[b], f);
        fadd_glb(&b_sum[b], bs);
    }
}

// One block per sample. Top-k threshold from count histogram via suffix scan.
__global__ __launch_bounds__(TPB_B) void pass_b(
    const unsigned* __restrict__ g_cnt, const float* __restrict__ f_sum,
    const float* __restrict__ b_sum, const float* __restrict__ gt_f_num,
    float* __restrict__ terms)
{
    __shared__ unsigned s_cnt[BINS];
    __shared__ unsigned s_suf[TPB_B];
    __shared__ double s_wsuf[TPB_B];
    __shared__ double s_dsum;

    const int b = blockIdx.x;
    const int t = threadIdx.x;

    // sum the 8 replicas
    #pragma unroll
    for (int j = 0; j < BINS_PER_CHUNK; ++j) {
        const int bin = j * TPB_B + t;
        unsigned c = 0;
        #pragma unroll
        for (int r = 0; r < REPL; ++r)
            c += g_cnt[((size_t)b * REPL + r) * BINS + bin];
        s_cnt[bin] = c;
    }
    __syncthreads();

    // per-chunk count and midpoint-weighted sum
    unsigned c = 0; double w = 0.0;
    const int cb = t * BINS_PER_CHUNK;
    #pragma unroll
    for (int j = 0; j < BINS_PER_CHUNK; ++j) {
        const unsigned cc = s_cnt[cb + j];
        c += cc;
        w += (double)cc * (double)(((float)(cb + j) + 0.5f) * BINW);
    }
    s_suf[t] = c; s_wsuf[t] = w;
    __syncthreads();

    // Hillis-Steele inclusive suffix scan over 256 chunks
    for (int off = 1; off < TPB_B; off <<= 1) {
        const unsigned ac = (t + off < TPB_B) ? s_suf[t + off] : 0u;
        const double aw = (t + off < TPB_B) ? s_wsuf[t + off] : 0.0;
        __syncthreads();
        s_suf[t] += ac; s_wsuf[t] += aw;
        __syncthreads();
    }

    const long long kk = (long long)gt_f_num[b];
    const unsigned long long n_pos = (unsigned long long)s_suf[0];
    const unsigned long long suf_me = s_suf[t];
    const unsigned long long suf_nx = (t + 1 < TPB_B) ? s_suf[t + 1] : 0ull;

    if (kk > 0 && (unsigned long long)kk < n_pos &&
        suf_nx < (unsigned long long)kk && (unsigned long long)kk <= suf_me) {
        unsigned long long cum = suf_nx;
        double W = (t + 1 < TPB_B) ? s_wsuf[t + 1] : 0.0;
        int bstar = cb;
        for (int j = BINS_PER_CHUNK - 1; j >= 0; --j) {
            const int bin = cb + j;
            const unsigned cc = s_cnt[bin];
            if (cum + cc >= (unsigned long long)kk) { bstar = bin; break; }
            cum += cc;
            W += (double)cc * (double)(((float)bin + 0.5f) * BINW);
        }
        const double partial = (double)(kk - (long long)cum);
        s_dsum = W + partial * (double)(((float)bstar + 0.5f) * BINW);
    }
    __syncthreads();

    if (t == 0) {
        const double S_total = (double)b_sum[b];   // exact
        const double fs = (double)f_sum[b];        // exact
        const double gfn = (double)gt_f_num[b];
        double dsum, dnum;
        if (kk <= 0) { dsum = 0.0; dnum = 0.0; }
        else if ((unsigned long long)kk >= n_pos) { dsum = S_total; dnum = (double)n_pos; }
        else { dsum = s_dsum; dnum = (double)kk; }
        const double term = dsum / (dnum + 1e-16)
                          + fs / (gfn + 1e-16)
                          + (S_total - dsum) / ((double)NPIX + 1e-16);
        terms[b] = (float)term;
    }
}

__global__ void pass_c(const float* __restrict__ terms, float* __restrict__ out)
{
    if (threadIdx.x == 0 && blockIdx.x == 0) {
        float s = 0.f;
        #pragma unroll
        for (int i = 0; i < NB; ++i) s += terms[i];
        out[0] = s / (float)NB;
    }
}

extern "C" void kernel_launch(void* const* d_in, const int* in_sizes, int n_in,
                              void* d_out, int out_size, void* d_ws, size_t ws_size,
                              hipStream_t stream) {
    const float* probs = (const float*)d_in[0];
    const float* gt    = (const float*)d_in[1];
    const float* gfn   = (const float*)d_in[2];
    char* ws = (char*)d_ws;

    const size_t hist_bytes = (size_t)NB * REPL * BINS * 4;   // 1 MB
    unsigned* g_cnt = (unsigned*)ws;
    float*    f_sum = (float*)(ws + hist_bytes);              // NB
    float*    b_sum = f_sum + NB;                             // NB
    float*    terms = b_sum + NB;                             // NB

    // zero g_cnt + f_sum + b_sum (ws is poisoned to 0xAA before every launch)
    hipMemsetAsync(ws, 0, hist_bytes + 2 * NB * sizeof(float), stream);

    hipLaunchKernelGGL(pass_a, dim3(NB * CHUNKS), dim3(TPB_A), 0, stream,
                       probs, gt, g_cnt, f_sum, b_sum);
    hipLaunchKernelGGL(pass_b, dim3(NB), dim3(TPB_B), 0, stream,
                       g_cnt, f_sum, b_sum, gfn, terms);
    hipLaunchKernelGGL(pass_c, dim3(1), dim3(64), 0, stream,
                       terms, (float*)d_out);
}

// Round 5
// 249.701 us; speedup vs baseline: 1.0039x; 1.0039x over previous
//
#include <hip/hip_runtime.h>
#include <math.h>

// Problem constants (match reference file)
#define NB 16
#define NPIX 1048576                        // 1024*1024
#define BINS 2048
#define CHUNKS 128                          // blocks per sample in pass A
#define TPB_A 256
#define PIX_PER_BLOCK (NPIX / CHUNKS)       // 8192
#define TILE_PX 1024                        // 256 thr * 4 px, 4 KB per stream
#define NT (PIX_PER_BLOCK / TILE_PX)        // 8 tiles per block
#define REPL 8                              // global histogram replicas per sample
#define TPB_B 256
#define BINS_PER_CHUNK (BINS / TPB_B)       // 8
#define BLOSS_MAX 16.7f                     // > B_CAP
#define BINW (BLOSS_MAX / (float)BINS)
#define B_CAP 16.636f                       // -log(2^-24): max -log(1-pc) after clip
#define F_CAP 16.1181f                      // -log(1e-7f)

__device__ __forceinline__ void fadd_glb(float* p, float v) {
    __hip_atomic_fetch_add(p, v, __ATOMIC_RELAXED, __HIP_MEMORY_SCOPE_AGENT);
}

// async global->LDS DMA, 16 B per lane (global_load_lds_dwordx4)
__device__ __forceinline__ void gl_lds16(const float* g, float* lds) {
    __builtin_amdgcn_global_load_lds(
        (const __attribute__((address_space(1))) unsigned*)g,
        (__attribute__((address_space(3))) unsigned*)lds, 16, 0, 0);
}

__global__ __launch_bounds__(TPB_A) void pass_a(
    const float* __restrict__ probs, const float* __restrict__ gt,
    unsigned* __restrict__ g_cnt, float* __restrict__ f_sum,
    float* __restrict__ b_sum)
{
    __shared__ unsigned s_cnt[BINS];            // 8 KB count histogram
    __shared__ float s_p0[2][TILE_PX];          // 2 x 4 KB
    __shared__ float s_p1[2][TILE_PX];
    __shared__ float s_g [2][TILE_PX];
    __shared__ float s_redf[TPB_A / 64];
    __shared__ float s_redb[TPB_A / 64];

    const int tid = threadIdx.x;
    #pragma unroll
    for (int j = 0; j < BINS / TPB_A; ++j) s_cnt[j * TPB_A + tid] = 0u;
    // first pipeline barrier (below) covers this zeroing

    const int blk = blockIdx.x;
    const int b = blk / CHUNKS;
    const int chunk = blk % CHUNKS;
    const float* p0 = probs + (size_t)b * 2 * NPIX;
    const float* p1 = p0 + NPIX;
    const float* gp = gt + (size_t)b * NPIX;
    const int base = chunk * PIX_PER_BLOCK;
    const float scale = (float)BINS / BLOSS_MAX;

    // issue tile DMA: per-lane 16 B from each of the 3 streams
    auto issue = [&](int t, int buf) {
        const int off = base + t * TILE_PX + (tid << 2);
        gl_lds16(p0 + off, &s_p0[buf][tid << 2]);
        gl_lds16(p1 + off, &s_p1[buf][tid << 2]);
        gl_lds16(gp + off, &s_g [buf][tid << 2]);
    };

    float f_acc = 0.f, b_acc = 0.f;
    issue(0, 0);
    for (int t = 0; t < NT; ++t) {
        // barrier drains DMA of tile t (issued one iteration ago -> latency
        // overlapped with process(t-1)); also syncs histogram zeroing at t=0
        __syncthreads();
        if (t + 1 < NT) issue(t + 1, (t + 1) & 1);   // un-drainable until NEXT barrier
        const int buf = t & 1;
        const float4 v0 = *(const float4*)&s_p0[buf][tid << 2];
        const float4 v1 = *(const float4*)&s_p1[buf][tid << 2];
        const float4 vg = *(const float4*)&s_g [buf][tid << 2];
        const float dv[4] = {v1.x - v0.x, v1.y - v0.y, v1.z - v0.z, v1.w - v0.w};
        const float gv[4] = {vg.x, vg.y, vg.z, vg.w};
        #pragma unroll
        for (int c = 0; c < 4; ++c) {
            // -log(1-sigmoid(d)) = softplus(d); -log(sigmoid(d)) = softplus(d)-d
            const float d = dv[c];
            const float g = gv[c];                  // exactly 0.0 or 1.0
            const float sp = fmaxf(d, 0.f) + __logf(1.f + __expf(-fabsf(d)));
            f_acc += g * fminf(sp - d, F_CAP);      // branchless fg loss
            const float bl = fminf(sp, B_CAP);
            b_acc += (1.f - g) * bl;                // branchless bg total
            if (g < 0.5f) {                         // only the atomic is predicated
                int bin = (int)(bl * scale);
                bin = bin < (BINS - 1) ? bin : (BINS - 1);
                atomicAdd(&s_cnt[bin], 1u);
            }
        }
    }
    __syncthreads();

    // flush count histogram into one of REPL replicated per-sample histograms
    {
        unsigned* dst = g_cnt + ((size_t)b * REPL + (chunk & (REPL - 1))) * BINS;
        #pragma unroll
        for (int j = 0; j < BINS / TPB_A; ++j) {
            const int bin = j * TPB_A + tid;
            const unsigned c = s_cnt[bin];
            if (c) atomicAdd(&dst[bin], c);
        }
    }

    // block-reduce f_acc / b_acc
    #pragma unroll
    for (int o = 32; o > 0; o >>= 1) {
        f_acc += __shfl_down(f_acc, o, 64);
        b_acc += __shfl_down(b_acc, o, 64);
    }
    if ((tid & 63) == 0) { s_redf[tid >> 6] = f_acc; s_redb[tid >> 6] = b_acc; }
    __syncthreads();
    if (tid == 0) {
        float f = 0.f, bs = 0.f;
        #pragma unroll
        for (int w = 0; w < TPB_A / 64; ++w) { f += s_redf[w]; bs += s_redb[w]; }
        fadd_glb(&f_sum[b], f);
        fadd_glb(&b_sum[b], bs);
    }
}

// One block per sample. Top-k threshold from count histogram via suffix scan.
__global__ __launch_bounds__(TPB_B) void pass_b(
    const unsigned* __restrict__ g_cnt, const float* __restrict__ f_sum,
    const float* __restrict__ b_sum, const float* __restrict__ gt_f_num,
    float* __restrict__ terms)
{
    __shared__ unsigned s_cnt[BINS];
    __shared__ unsigned s_suf[TPB_B];
    __shared__ double s_wsuf[TPB_B];
    __shared__ double s_dsum;

    const int b = blockIdx.x;
    const int t = threadIdx.x;

    // sum the replicas
    #pragma unroll
    for (int j = 0; j < BINS_PER_CHUNK; ++j) {
        const int bin = j * TPB_B + t;
        unsigned c = 0;
        #pragma unroll
        for (int r = 0; r < REPL; ++r)
            c += g_cnt[((size_t)b * REPL + r) * BINS + bin];
        s_cnt[bin] = c;
    }
    __syncthreads();

    // per-chunk count and midpoint-weighted sum
    unsigned c = 0; double w = 0.0;
    const int cb = t * BINS_PER_CHUNK;
    #pragma unroll
    for (int j = 0; j < BINS_PER_CHUNK; ++j) {
        const unsigned cc = s_cnt[cb + j];
        c += cc;
        w += (double)cc * (double)(((float)(cb + j) + 0.5f) * BINW);
    }
    s_suf[t] = c; s_wsuf[t] = w;
    __syncthreads();

    // Hillis-Steele inclusive suffix scan over 256 chunks
    for (int off = 1; off < TPB_B; off <<= 1) {
        const unsigned ac = (t + off < TPB_B) ? s_suf[t + off] : 0u;
        const double aw = (t + off < TPB_B) ? s_wsuf[t + off] : 0.0;
        __syncthreads();
        s_suf[t] += ac; s_wsuf[t] += aw;
        __syncthreads();
    }

    const long long kk = (long long)gt_f_num[b];
    const unsigned long long n_pos = (unsigned long long)s_suf[0];
    const unsigned long long suf_me = s_suf[t];
    const unsigned long long suf_nx = (t + 1 < TPB_B) ? s_suf[t + 1] : 0ull;

    if (kk > 0 && (unsigned long long)kk < n_pos &&
        suf_nx < (unsigned long long)kk && (unsigned long long)kk <= suf_me) {
        unsigned long long cum = suf_nx;
        double W = (t + 1 < TPB_B) ? s_wsuf[t + 1] : 0.0;
        int bstar = cb;
        for (int j = BINS_PER_CHUNK - 1; j >= 0; --j) {
            const int bin = cb + j;
            const unsigned cc = s_cnt[bin];
            if (cum + cc >= (unsigned long long)kk) { bstar = bin; break; }
            cum += cc;
            W += (double)cc * (double)(((float)bin + 0.5f) * BINW);
        }
        const double partial = (double)(kk - (long long)cum);
        s_dsum = W + partial * (double)(((float)bstar + 0.5f) * BINW);
    }
    __syncthreads();

    if (t == 0) {
        const double S_total = (double)b_sum[b];   // exact
        const double fs = (double)f_sum[b];        // exact
        const double gfn = (double)gt_f_num[b];
        double dsum, dnum;
        if (kk <= 0) { dsum = 0.0; dnum = 0.0; }
        else if ((unsigned long long)kk >= n_pos) { dsum = S_total; dnum = (double)n_pos; }
        else { dsum = s_dsum; dnum = (double)kk; }
        const double term = dsum / (dnum + 1e-16)
                          + fs / (gfn + 1e-16)
                          + (S_total - dsum) / ((double)NPIX + 1e-16);
        terms[b] = (float)term;
    }
}

__global__ void pass_c(const float* __restrict__ terms, float* __restrict__ out)
{
    if (threadIdx.x == 0 && blockIdx.x == 0) {
        float s = 0.f;
        #pragma unroll
        for (int i = 0; i < NB; ++i) s += terms[i];
        out[0] = s / (float)NB;
    }
}

extern "C" void kernel_launch(void* const* d_in, const int* in_sizes, int n_in,
                              void* d_out, int out_size, void* d_ws, size_t ws_size,
                              hipStream_t stream) {
    const float* probs = (const float*)d_in[0];
    const float* gt    = (const float*)d_in[1];
    const float* gfn   = (const float*)d_in[2];
    char* ws = (char*)d_ws;

    const size_t hist_bytes = (size_t)NB * REPL * BINS * 4;   // 1 MB
    unsigned* g_cnt = (unsigned*)ws;
    float*    f_sum = (float*)(ws + hist_bytes);              // NB
    float*    b_sum = f_sum + NB;                             // NB
    float*    terms = b_sum + NB;                             // NB

    // zero g_cnt + f_sum + b_sum (ws is poisoned to 0xAA before every launch)
    hipMemsetAsync(ws, 0, hist_bytes + 2 * NB * sizeof(float), stream);

    hipLaunchKernelGGL(pass_a, dim3(NB * CHUNKS), dim3(TPB_A), 0, stream,
                       probs, gt, g_cnt, f_sum, b_sum);
    hipLaunchKernelGGL(pass_b, dim3(NB), dim3(TPB_B), 0, stream,
                       g_cnt, f_sum, b_sum, gfn, terms);
    hipLaunchKernelGGL(pass_c, dim3(1), dim3(64), 0, stream,
                       terms, (float*)d_out);
}

// Round 6
// 248.506 us; speedup vs baseline: 1.0087x; 1.0048x over previous
//
#include <hip/hip_runtime.h>
#include <math.h>

// Problem constants (match reference file)
#define NB 16
#define NPIX 1048576                        // 1024*1024
#define BINS 2048
#define CHUNKS 128                          // blocks per sample in pass A
#define TPB_A 512
#define PIX_PER_BLOCK (NPIX / CHUNKS)       // 8192
#define PPT 16                              // px per thread
#define ITERS (PIX_PER_BLOCK / (TPB_A * 4)) // 4 float4-triple iterations
#define REPL 8                              // global histogram replicas per sample
#define TPB_B 256
#define BINS_PER_CHUNK (BINS / TPB_B)       // 8
// d-space binning: bl = softplus(d) is monotone in d = p1 - p0
#define D_LO   (-10.24f)
#define D_SCALE (100.0f)                    // 1/binwidth, binwidth = 0.01
#define D_BIAS  (1024.0f)                   // -D_LO * D_SCALE
#define BINW_D  (0.01f)

__global__ __launch_bounds__(TPB_A) void pass_a(
    const float* __restrict__ probs, const float* __restrict__ gt,
    unsigned* __restrict__ g_cnt)
{
    __shared__ unsigned s_cnt[BINS];          // 8 KB packed histogram: fg<<16 | bg

    const int tid = threadIdx.x;
    #pragma unroll
    for (int j = 0; j < BINS / TPB_A; ++j) s_cnt[j * TPB_A + tid] = 0u;
    __syncthreads();

    const int blk = blockIdx.x;
    const int b = blk / CHUNKS;
    const int chunk = blk % CHUNKS;
    const float* p0 = probs + (size_t)b * 2 * NPIX;
    const float* p1 = p0 + NPIX;
    const float* gp = gt + (size_t)b * NPIX;
    const int base = chunk * PIX_PER_BLOCK;

    #pragma unroll
    for (int it = 0; it < ITERS; ++it) {
        const int i = base + ((it * TPB_A + tid) << 2);
        const float4 v0 = *(const float4*)(p0 + i);
        const float4 v1 = *(const float4*)(p1 + i);
        const float4 vg = *(const float4*)(gp + i);
        const float dv[4] = {v1.x - v0.x, v1.y - v0.y, v1.z - v0.z, v1.w - v0.w};
        const float gv[4] = {vg.x, vg.y, vg.z, vg.w};
        #pragma unroll
        for (int c = 0; c < 4; ++c) {
            // branchless: bin on d (monotone with b_loss); fg in hi16, bg in lo16
            int bin = (int)fmaf(dv[c], D_SCALE, D_BIAS);
            bin = bin < 0 ? 0 : (bin > BINS - 1 ? BINS - 1 : bin);
            const unsigned inc = (gv[c] > 0.5f) ? 0x10000u : 1u;
            atomicAdd(&s_cnt[bin], inc);
        }
    }
    __syncthreads();

    // flush packed histogram into one of REPL replicated per-sample histograms
    unsigned* dst = g_cnt + ((size_t)b * REPL + (chunk & (REPL - 1))) * BINS;
    #pragma unroll
    for (int j = 0; j < BINS / TPB_A; ++j) {
        const int bin = j * TPB_A + tid;
        const unsigned c = s_cnt[bin];
        if (c) atomicAdd(&dst[bin], c);
    }
}

__device__ __forceinline__ float softplus_ref(float m) {
    // accurate softplus for bin midpoints (pass_b only, 2048 evals)
    return fmaxf(m, 0.f) + log1pf(__expf(-fabsf(m)));
}

// One block per sample: reconstruct all three loss terms from the histogram.
__global__ __launch_bounds__(TPB_B) void pass_b(
    const unsigned* __restrict__ g_cnt, const float* __restrict__ gt_f_num,
    float* __restrict__ terms)
{
    __shared__ unsigned s_cnt[BINS];          // packed per-sample histogram
    __shared__ unsigned s_suf[TPB_B];         // suffix-scan: bg counts
    __shared__ double s_wsuf[TPB_B];          // suffix-scan: bg * sp(mid)
    __shared__ double s_fred[TPB_B];          // fg * (sp(mid) - mid) reduction
    __shared__ double s_dsum;

    const int b = blockIdx.x;
    const int t = threadIdx.x;

    // sum the replicas
    #pragma unroll
    for (int j = 0; j < BINS_PER_CHUNK; ++j) {
        const int bin = j * TPB_B + t;
        unsigned c = 0;
        #pragma unroll
        for (int r = 0; r < REPL; ++r)
            c += g_cnt[((size_t)b * REPL + r) * BINS + bin];
        s_cnt[bin] = c;
    }
    __syncthreads();

    // per-chunk: bg count, bg weighted sum, fg loss sum
    unsigned c = 0; double w = 0.0, f = 0.0;
    const int cb = t * BINS_PER_CHUNK;
    #pragma unroll
    for (int j = 0; j < BINS_PER_CHUNK; ++j) {
        const unsigned pk = s_cnt[cb + j];
        const unsigned bg = pk & 0xFFFFu, fg = pk >> 16;
        const float m = fmaf((float)(cb + j) + 0.5f, BINW_D, D_LO);
        const float sp = softplus_ref(m);
        c += bg;
        w += (double)bg * (double)sp;
        f += (double)fg * (double)(sp - m);
    }
    s_suf[t] = c; s_wsuf[t] = w; s_fred[t] = f;
    __syncthreads();

    // Hillis-Steele inclusive suffix scan over 256 chunks (bg cnt + weighted)
    for (int off = 1; off < TPB_B; off <<= 1) {
        const unsigned ac = (t + off < TPB_B) ? s_suf[t + off] : 0u;
        const double aw = (t + off < TPB_B) ? s_wsuf[t + off] : 0.0;
        const double af = (t + off < TPB_B) ? s_fred[t + off] : 0.0;
        __syncthreads();
        s_suf[t] += ac; s_wsuf[t] += aw; s_fred[t] += af;
        __syncthreads();
    }

    const long long kk = (long long)gt_f_num[b];
    const unsigned long long n_pos = (unsigned long long)s_suf[0];
    const unsigned long long suf_me = s_suf[t];
    const unsigned long long suf_nx = (t + 1 < TPB_B) ? s_suf[t + 1] : 0ull;

    if (kk > 0 && (unsigned long long)kk < n_pos &&
        suf_nx < (unsigned long long)kk && (unsigned long long)kk <= suf_me) {
        // threshold bin in my chunk; top-down refine
        unsigned long long cum = suf_nx;
        double W = (t + 1 < TPB_B) ? s_wsuf[t + 1] : 0.0;
        int bstar = cb;
        for (int j = BINS_PER_CHUNK - 1; j >= 0; --j) {
            const int bin = cb + j;
            const unsigned bg = s_cnt[bin] & 0xFFFFu;
            if (cum + bg >= (unsigned long long)kk) { bstar = bin; break; }
            cum += bg;
            const float m = fmaf((float)bin + 0.5f, BINW_D, D_LO);
            W += (double)bg * (double)softplus_ref(m);
        }
        const double partial = (double)(kk - (long long)cum);
        const float mstar = fmaf((float)bstar + 0.5f, BINW_D, D_LO);
        s_dsum = W + partial * (double)softplus_ref(mstar);
    }
    __syncthreads();

    if (t == 0) {
        const double S_total = s_wsuf[0];      // sum of bg losses (midpoint)
        const double fs = s_fred[0];           // sum of fg losses (midpoint)
        const double gfn = (double)gt_f_num[b];
        double dsum, dnum;
        if (kk <= 0) { dsum = 0.0; dnum = 0.0; }
        else if ((unsigned long long)kk >= n_pos) { dsum = S_total; dnum = (double)n_pos; }
        else { dsum = s_dsum; dnum = (double)kk; }
        const double term = dsum / (dnum + 1e-16)
                          + fs / (gfn + 1e-16)
                          + (S_total - dsum) / ((double)NPIX + 1e-16);
        terms[b] = (float)term;
    }
}

__global__ void pass_c(const float* __restrict__ terms, float* __restrict__ out)
{
    if (threadIdx.x == 0 && blockIdx.x == 0) {
        float s = 0.f;
        #pragma unroll
        for (int i = 0; i < NB; ++i) s += terms[i];
        out[0] = s / (float)NB;
    }
}

extern "C" void kernel_launch(void* const* d_in, const int* in_sizes, int n_in,
                              void* d_out, int out_size, void* d_ws, size_t ws_size,
                              hipStream_t stream) {
    const float* probs = (const float*)d_in[0];
    const float* gt    = (const float*)d_in[1];
    const float* gfn   = (const float*)d_in[2];
    char* ws = (char*)d_ws;

    const size_t hist_bytes = (size_t)NB * REPL * BINS * 4;   // 1 MB
    unsigned* g_cnt = (unsigned*)ws;
    float*    terms = (float*)(ws + hist_bytes);              // NB floats

    // zero g_cnt (ws is poisoned to 0xAA before every launch)
    hipMemsetAsync(ws, 0, hist_bytes, stream);

    hipLaunchKernelGGL(pass_a, dim3(NB * CHUNKS), dim3(TPB_A), 0, stream,
                       probs, gt, g_cnt);
    hipLaunchKernelGGL(pass_b, dim3(NB), dim3(TPB_B), 0, stream,
                       g_cnt, gfn, terms);
    hipLaunchKernelGGL(pass_c, dim3(1), dim3(64), 0, stream,
                       terms, (float*)d_out);
}